// Round 17
// baseline (115.486 us; speedup 1.0000x reference)
//
#include <hip/hip_runtime.h>
#include <math.h>

#define N_G 10000
#define NPAD 10112          // 79 tiles * 128
#define C_DIM 8
#define J_DIM 16
#define K_DIM 128           // C*J
#define KP 128              // plain fp16
#define H_IMG 512
#define W_IMG 512
#define HW_IMG (H_IMG*W_IMG)
#define IMG_SIZE (3*HW_IMG)
#define NTILE 79            // NPAD/128
#define NGEMM (NTILE*NTILE) // 6241
#define LSTRIDE 132         // 128 + 4 floats: 16B-aligned rows, bank-spread

typedef unsigned short u16;
typedef _Float16 f16x8 __attribute__((ext_vector_type(8)));
typedef float f32x4 __attribute__((ext_vector_type(4)));

__device__ inline u16 f2h(float x) {
    union { _Float16 h; u16 u; } v; v.h = (_Float16)x; return v.u;
}

// ================= fused: preprocess | repack_psi | zero_img =================
// blocks 0..39: preprocess (U fp16, detail); 40..79: repack psi; 80..847: zero img
__global__ __launch_bounds__(256)
void prep_zero(const float* __restrict__ alog,    // [N,8]
               const float* __restrict__ wproj,   // [N,128]
               const float* __restrict__ psi,     // [N,128]
               const float* __restrict__ cbases,  // [8,16,2]
               u16*   __restrict__ Up,            // ws [NPAD,128] f16
               u16*   __restrict__ Pp,            // ws [NPAD,128] f16
               float* __restrict__ detail_out,    // out [N,2]
               float* __restrict__ img)           // out [3,512,512]
{
    const int bid = blockIdx.x;
    const int tid = threadIdx.x;

    if (bid >= 80) {                               // ---- zero image ----
        ((float4*)img)[(size_t)(bid - 80) * 256 + tid] = make_float4(0.f,0.f,0.f,0.f);
        return;
    }

    if (bid >= 40) {                               // ---- repack psi -> fp16 ----
        int m = (bid - 40) * 256 + tid;
        if (m >= NPAD) return;
        u16* pr = Pp + (size_t)m * KP;
        if (m >= N_G) {
            uint4 z = make_uint4(0,0,0,0);
            uint4* p = (uint4*)pr;
            #pragma unroll
            for (int i = 0; i < 16; ++i) p[i] = z;
            return;
        }
        const float4* ps = (const float4*)(psi + (size_t)m * K_DIM);
        #pragma unroll
        for (int q = 0; q < 32; ++q) {
            float4 x = ps[q];
            uint2 hv;
            hv.x = (unsigned)f2h(x.x) | ((unsigned)f2h(x.y)<<16);
            hv.y = (unsigned)f2h(x.z) | ((unsigned)f2h(x.w)<<16);
            *(uint2*)(pr + q*4) = hv;
        }
        return;
    }

    // ---- preprocess: softmax, detail, U fp16 ----
    int n = bid * 256 + tid;
    if (n >= NPAD) return;
    u16* ur = Up + (size_t)n * KP;
    if (n >= N_G) {
        uint4 z = make_uint4(0,0,0,0);
        uint4* p = (uint4*)ur;
        #pragma unroll
        for (int i = 0; i < 16; ++i) p[i] = z;
        return;
    }

    float al[C_DIM];
    const float4* ap = (const float4*)(alog + n * C_DIM);
    float4 a0 = ap[0], a1 = ap[1];
    al[0]=a0.x; al[1]=a0.y; al[2]=a0.z; al[3]=a0.w;
    al[4]=a1.x; al[5]=a1.y; al[6]=a1.z; al[7]=a1.w;
    float mx = al[0];
    #pragma unroll
    for (int c = 1; c < C_DIM; ++c) mx = fmaxf(mx, al[c]);
    float s = 0.f;
    #pragma unroll
    for (int c = 0; c < C_DIM; ++c) { al[c] = expf(al[c] - mx); s += al[c]; }
    float inv = 1.f / s;
    #pragma unroll
    for (int c = 0; c < C_DIM; ++c) al[c] *= inv;

    float d0 = 0.f, d1 = 0.f;
    const float4* wp = (const float4*)(wproj + (size_t)n * K_DIM);
    #pragma unroll
    for (int c = 0; c < C_DIM; ++c) {
        float ac = al[c];
        #pragma unroll
        for (int q = 0; q < J_DIM/4; ++q) {
            float4 w4 = wp[c*4+q];
            float4 u4;
            u4.x = ac*w4.x; u4.y = ac*w4.y; u4.z = ac*w4.z; u4.w = ac*w4.w;
            int lb = (c*J_DIM + q*4) * 2;
            d0 = fmaf(u4.x, cbases[lb+0], d0); d1 = fmaf(u4.x, cbases[lb+1], d1);
            d0 = fmaf(u4.y, cbases[lb+2], d0); d1 = fmaf(u4.y, cbases[lb+3], d1);
            d0 = fmaf(u4.z, cbases[lb+4], d0); d1 = fmaf(u4.z, cbases[lb+5], d1);
            d0 = fmaf(u4.w, cbases[lb+6], d0); d1 = fmaf(u4.w, cbases[lb+7], d1);
            uint2 hv;
            hv.x = (unsigned)f2h(u4.x) | ((unsigned)f2h(u4.y)<<16);
            hv.y = (unsigned)f2h(u4.z) | ((unsigned)f2h(u4.w)<<16);
            *(uint2*)(ur + c*J_DIM + q*4) = hv;
        }
    }
    detail_out[n*2+0] = d0;
    detail_out[n*2+1] = d1;
}

// ================= MFMA GEMM + raster tail =================
// 128x128 tile, 4 waves 2x2, 16x16x32 MFMA, global_load_lds + src-swizzle.
// PLAIN GLOBAL ROW-MAJOR block order; epilogue LDS transpose -> 512B runs,
// PLAIN stores (A/B vs nt under the cooperative order: L2 merges the
// 64B-misaligned odd-row partial lines from adjacent blocks).
#define TILE 128

__global__ __launch_bounds__(256)
void gemm_raster(const u16* __restrict__ U, const u16* __restrict__ P,
                 const float* __restrict__ alog,
                 const float* __restrict__ xyz,
                 const float* __restrict__ chol,
                 const float* __restrict__ opac,
                 const float* __restrict__ cmeans,
                 float* __restrict__ D, float* __restrict__ img)
{
    __shared__ char smem[32768];
    char* As = smem;            // [128][128B] f16, XOR-swizzled content
    char* Bs = smem + 16384;

    const int t = threadIdx.x;
    const int w = t >> 6;       // wave 0..3
    const int l = t & 63;

    // ---- plain global row-major order ----
    const int orig = blockIdx.x;
    const int row = orig / NTILE;
    const int col = orig - row * NTILE;
    const long bm = (long)row * TILE;
    const long bn = (long)col * TILE;
    const int wm = (w >> 1) * 64;
    const int wn = (w & 1) * 64;

    const char* Ub = (const char*)U;
    const char* Pb = (const char*)P;

    const int inner = ((l & 7) * 16) ^ (((l >> 3) & 7) << 4);
    const int fr  = l & 15;            // within-16 row index
    const int g   = l >> 4;            // k-group 0..3
    const int fx  = g * 16;
    const int swz = (l & 7) << 4;

    f32x4 acc[4][4];
    #pragma unroll
    for (int i = 0; i < 4; ++i)
        #pragma unroll
        for (int j = 0; j < 4; ++j)
            acc[i][j] = (f32x4){0.f, 0.f, 0.f, 0.f};

    #pragma unroll
    for (int it = 0; it < 2; ++it) {
        const long kbyte = (long)it * 128;
        #pragma unroll
        for (int c = 0; c < 4; ++c) {
            const int rc = (w*4 + c)*8 + (l >> 3);
            const char* ga = Ub + (bm + rc)*256 + kbyte + inner;
            const char* gb = Pb + (bn + rc)*256 + kbyte + inner;
            __builtin_amdgcn_global_load_lds(
                (const __attribute__((address_space(1))) void*)ga,
                (__attribute__((address_space(3))) void*)(As + (w*4+c)*1024), 16, 0, 0);
            __builtin_amdgcn_global_load_lds(
                (const __attribute__((address_space(1))) void*)gb,
                (__attribute__((address_space(3))) void*)(Bs + (w*4+c)*1024), 16, 0, 0);
        }
        __syncthreads();
        #pragma unroll
        for (int kk = 0; kk < 2; ++kk) {
            f16x8 a[4], b[4];
            #pragma unroll
            for (int i = 0; i < 4; ++i) {
                const int rowa = wm + i*16 + fr;
                a[i] = *(const f16x8*)(As + rowa*128 + ((kk*64 + fx) ^ swz));
                const int rowb = wn + i*16 + fr;
                b[i] = *(const f16x8*)(Bs + rowb*128 + ((kk*64 + fx) ^ swz));
            }
            // transposed: mfma(b,a) so lane holds 4 consecutive D cols
            #pragma unroll
            for (int i = 0; i < 4; ++i)
                #pragma unroll
                for (int j = 0; j < 4; ++j)
                    acc[i][j] = __builtin_amdgcn_mfma_f32_16x16x32_f16(b[j], a[i], acc[i][j], 0, 0, 0);
        }
        __syncthreads();
    }

    // ---- epilogue: LDS transpose in 32-row quarters -> contiguous plain stores ----
    float* lbuf = (float*)smem;
    #pragma unroll
    for (int q = 0; q < 4; ++q) {
        if ((w >> 1) == (q >> 1)) {
            const int ib = (q & 1) * 2;
            #pragma unroll
            for (int ii = 0; ii < 2; ++ii) {
                const int rl = ii*16 + fr;
                #pragma unroll
                for (int j = 0; j < 4; ++j) {
                    const int cl = wn + j*16 + g*4;
                    *(f32x4*)(lbuf + rl*LSTRIDE + cl) = acc[ib+ii][j];
                }
            }
        }
        __syncthreads();
        const int qrow0 = (int)bm + q*32;
        const int c4 = (t & 31) * 4;
        #pragma unroll
        for (int p = 0; p < 4; ++p) {
            const int rl = p*8 + (t >> 5);
            const int drow = qrow0 + rl;
            const int dcol = (int)bn + c4;
            f32x4 v = *(const f32x4*)(lbuf + rl*LSTRIDE + c4);
            if (drow < N_G && dcol < N_G)
                *(f32x4*)(D + (size_t)drow * N_G + dcol) = v;
        }
        __syncthreads();
    }

    // ---- raster tail: blocks orig<5000 raster gaussians 2*orig, 2*orig+1 ----
    if (orig >= 5000) return;
    #pragma unroll
    for (int g2 = 0; g2 < 2; ++g2) {
        const int n = orig * 2 + g2;
        float al[C_DIM];
        const float4* ap = (const float4*)(alog + n * C_DIM);
        float4 a0 = ap[0], a1 = ap[1];
        al[0]=a0.x; al[1]=a0.y; al[2]=a0.z; al[3]=a0.w;
        al[4]=a1.x; al[5]=a1.y; al[6]=a1.z; al[7]=a1.w;
        float mx = al[0];
        #pragma unroll
        for (int c = 1; c < C_DIM; ++c) mx = fmaxf(mx, al[c]);
        float s = 0.f;
        #pragma unroll
        for (int c = 0; c < C_DIM; ++c) { al[c] = expf(al[c] - mx); s += al[c]; }
        float inv = 1.f / s;
        float r = 0.f, gg = 0.f, b = 0.f;
        #pragma unroll
        for (int c = 0; c < C_DIM; ++c) {
            float ac = al[c] * inv;
            r  += ac * cmeans[c*3+0];
            gg += ac * cmeans[c*3+1];
            b  += ac * cmeans[c*3+2];
        }
        float px = 0.5f * W_IMG * (xyz[n*2+0] + 1.f);
        float py = 0.5f * H_IMG * (xyz[n*2+1] + 1.f);
        float l0 = chol[n*3+0] + 0.5f;
        float l1 = chol[n*3+1];
        float l2 = chol[n*3+2] + 0.5f;
        float c00 = l0*l0, c01 = l0*l1, c11 = l1*l1 + l2*l2;
        float det = c00*c11 - c01*c01;
        float idet = 1.f / det;
        float q0 = c11*idet, q1 = -c01*idet, q2 = c00*idet;
        float op = opac[n];
        int bx = (int)floorf(px);
        int by = (int)floorf(py);

        #pragma unroll
        for (int i = 0; i < 4; ++i) {
            int pix = t + i * 256;
            int tyi = pix >> 5;
            int txi = pix & 31;
            int xi = bx - 16 + txi;
            int yi = by - 16 + tyi;
            float dx = px - ((float)xi + 0.5f);
            float dy = py - ((float)yi + 0.5f);
            float sigma = 0.5f * (q0*dx*dx + q2*dy*dy) + q1*dx*dy;
            float a = fminf(0.999f, op * expf(-sigma));
            bool valid = (sigma >= 0.f) && (a > (1.0f/255.0f)) &&
                         (yi >= 0) && (yi < H_IMG) && (xi >= 0) && (xi < W_IMG);
            if (valid) {
                int idx = yi * W_IMG + xi;
                atomicAdd(img + idx,            a * r);
                atomicAdd(img + HW_IMG + idx,   a * gg);
                atomicAdd(img + 2*HW_IMG + idx, a * b);
            }
        }
    }
}

extern "C" void kernel_launch(void* const* d_in, const int* in_sizes, int n_in,
                              void* d_out, int out_size, void* d_ws, size_t ws_size,
                              hipStream_t stream) {
    const float* alog   = (const float*)d_in[0];
    const float* wproj  = (const float*)d_in[1];
    const float* psi    = (const float*)d_in[2];
    const float* xyz    = (const float*)d_in[3];
    const float* chol   = (const float*)d_in[4];
    const float* opac   = (const float*)d_in[5];
    const float* cmeans = (const float*)d_in[6];
    const float* cbases = (const float*)d_in[7];

    float* out  = (float*)d_out;
    float* img  = out;                                    // [3,512,512]
    float* dmat = out + IMG_SIZE;                         // [N,N]
    float* det  = out + IMG_SIZE + (size_t)N_G * N_G;     // [N,2]

    u16*   Up     = (u16*)d_ws;                           // [NPAD,128]
    u16*   Pp     = Up + (size_t)NPAD * KP;               // [NPAD,128]

    prep_zero<<<848, 256, 0, stream>>>(
        alog, wproj, psi, cbases, Up, Pp, det, img);

    gemm_raster<<<NGEMM, 256, 0, stream>>>(
        Up, Pp, alog, xyz, chol, opac, cmeans, dmat, img);
}

// Round 18
// 91.190 us; speedup vs baseline: 1.2664x; 1.2664x over previous
//
#include <hip/hip_runtime.h>
#include <math.h>

#define N_G 10000
#define NPAD 10112          // 79 tiles * 128
#define C_DIM 8
#define J_DIM 16
#define K_DIM 128           // C*J
#define KP 128              // plain fp16
#define H_IMG 512
#define W_IMG 512
#define HW_IMG (H_IMG*W_IMG)
#define IMG_SIZE (3*HW_IMG)
#define NTILE 79            // NPAD/128
#define NGEMM (NTILE*NTILE) // 6241
#define LSTRIDE 132         // 128 + 4 floats: 16B-aligned rows, bank-spread

typedef unsigned short u16;
typedef _Float16 f16x8 __attribute__((ext_vector_type(8)));
typedef float f32x4 __attribute__((ext_vector_type(4)));

__device__ inline u16 f2h(float x) {
    union { _Float16 h; u16 u; } v; v.h = (_Float16)x; return v.u;
}

// ================= fused: preprocess | repack_psi | zero_img =================
// blocks 0..39: preprocess (U fp16, detail); 40..79: repack psi; 80..847: zero img
__global__ __launch_bounds__(256)
void prep_zero(const float* __restrict__ alog,    // [N,8]
               const float* __restrict__ wproj,   // [N,128]
               const float* __restrict__ psi,     // [N,128]
               const float* __restrict__ cbases,  // [8,16,2]
               u16*   __restrict__ Up,            // ws [NPAD,128] f16
               u16*   __restrict__ Pp,            // ws [NPAD,128] f16
               float* __restrict__ detail_out,    // out [N,2]
               float* __restrict__ img)           // out [3,512,512]
{
    const int bid = blockIdx.x;
    const int tid = threadIdx.x;

    if (bid >= 80) {                               // ---- zero image ----
        ((float4*)img)[(size_t)(bid - 80) * 256 + tid] = make_float4(0.f,0.f,0.f,0.f);
        return;
    }

    if (bid >= 40) {                               // ---- repack psi -> fp16 ----
        int m = (bid - 40) * 256 + tid;
        if (m >= NPAD) return;
        u16* pr = Pp + (size_t)m * KP;
        if (m >= N_G) {
            uint4 z = make_uint4(0,0,0,0);
            uint4* p = (uint4*)pr;
            #pragma unroll
            for (int i = 0; i < 16; ++i) p[i] = z;
            return;
        }
        const float4* ps = (const float4*)(psi + (size_t)m * K_DIM);
        #pragma unroll
        for (int q = 0; q < 32; ++q) {
            float4 x = ps[q];
            uint2 hv;
            hv.x = (unsigned)f2h(x.x) | ((unsigned)f2h(x.y)<<16);
            hv.y = (unsigned)f2h(x.z) | ((unsigned)f2h(x.w)<<16);
            *(uint2*)(pr + q*4) = hv;
        }
        return;
    }

    // ---- preprocess: softmax, detail, U fp16 ----
    int n = bid * 256 + tid;
    if (n >= NPAD) return;
    u16* ur = Up + (size_t)n * KP;
    if (n >= N_G) {
        uint4 z = make_uint4(0,0,0,0);
        uint4* p = (uint4*)ur;
        #pragma unroll
        for (int i = 0; i < 16; ++i) p[i] = z;
        return;
    }

    float al[C_DIM];
    const float4* ap = (const float4*)(alog + n * C_DIM);
    float4 a0 = ap[0], a1 = ap[1];
    al[0]=a0.x; al[1]=a0.y; al[2]=a0.z; al[3]=a0.w;
    al[4]=a1.x; al[5]=a1.y; al[6]=a1.z; al[7]=a1.w;
    float mx = al[0];
    #pragma unroll
    for (int c = 1; c < C_DIM; ++c) mx = fmaxf(mx, al[c]);
    float s = 0.f;
    #pragma unroll
    for (int c = 0; c < C_DIM; ++c) { al[c] = expf(al[c] - mx); s += al[c]; }
    float inv = 1.f / s;
    #pragma unroll
    for (int c = 0; c < C_DIM; ++c) al[c] *= inv;

    float d0 = 0.f, d1 = 0.f;
    const float4* wp = (const float4*)(wproj + (size_t)n * K_DIM);
    #pragma unroll
    for (int c = 0; c < C_DIM; ++c) {
        float ac = al[c];
        #pragma unroll
        for (int q = 0; q < J_DIM/4; ++q) {
            float4 w4 = wp[c*4+q];
            float4 u4;
            u4.x = ac*w4.x; u4.y = ac*w4.y; u4.z = ac*w4.z; u4.w = ac*w4.w;
            int lb = (c*J_DIM + q*4) * 2;
            d0 = fmaf(u4.x, cbases[lb+0], d0); d1 = fmaf(u4.x, cbases[lb+1], d1);
            d0 = fmaf(u4.y, cbases[lb+2], d0); d1 = fmaf(u4.y, cbases[lb+3], d1);
            d0 = fmaf(u4.z, cbases[lb+4], d0); d1 = fmaf(u4.z, cbases[lb+5], d1);
            d0 = fmaf(u4.w, cbases[lb+6], d0); d1 = fmaf(u4.w, cbases[lb+7], d1);
            uint2 hv;
            hv.x = (unsigned)f2h(u4.x) | ((unsigned)f2h(u4.y)<<16);
            hv.y = (unsigned)f2h(u4.z) | ((unsigned)f2h(u4.w)<<16);
            *(uint2*)(ur + c*J_DIM + q*4) = hv;
        }
    }
    detail_out[n*2+0] = d0;
    detail_out[n*2+1] = d1;
}

// ================= MFMA GEMM + raster tail =================
// 128x128 tile, 4 waves 2x2, 16x16x32 MFMA, global_load_lds + src-swizzle.
// PLAIN GLOBAL ROW-MAJOR block order: device's ~1280 concurrent blocks sweep
// ~16 contiguous tile-rows -> globally near-sequential D writes.
// Epilogue: LDS transpose (32-row quarters) -> 512B-run nt stores.
#define TILE 128

__global__ __launch_bounds__(256)
void gemm_raster(const u16* __restrict__ U, const u16* __restrict__ P,
                 const float* __restrict__ alog,
                 const float* __restrict__ xyz,
                 const float* __restrict__ chol,
                 const float* __restrict__ opac,
                 const float* __restrict__ cmeans,
                 float* __restrict__ D, float* __restrict__ img)
{
    __shared__ char smem[32768];
    char* As = smem;            // [128][128B] f16, XOR-swizzled content
    char* Bs = smem + 16384;

    const int t = threadIdx.x;
    const int w = t >> 6;       // wave 0..3
    const int l = t & 63;

    // ---- plain global row-major order ----
    const int orig = blockIdx.x;
    const int row = orig / NTILE;
    const int col = orig - row * NTILE;
    const long bm = (long)row * TILE;
    const long bn = (long)col * TILE;
    const int wm = (w >> 1) * 64;
    const int wn = (w & 1) * 64;

    const char* Ub = (const char*)U;
    const char* Pb = (const char*)P;

    const int inner = ((l & 7) * 16) ^ (((l >> 3) & 7) << 4);
    const int fr  = l & 15;            // within-16 row index
    const int g   = l >> 4;            // k-group 0..3
    const int fx  = g * 16;
    const int swz = (l & 7) << 4;

    f32x4 acc[4][4];
    #pragma unroll
    for (int i = 0; i < 4; ++i)
        #pragma unroll
        for (int j = 0; j < 4; ++j)
            acc[i][j] = (f32x4){0.f, 0.f, 0.f, 0.f};

    #pragma unroll
    for (int it = 0; it < 2; ++it) {
        const long kbyte = (long)it * 128;
        #pragma unroll
        for (int c = 0; c < 4; ++c) {
            const int rc = (w*4 + c)*8 + (l >> 3);
            const char* ga = Ub + (bm + rc)*256 + kbyte + inner;
            const char* gb = Pb + (bn + rc)*256 + kbyte + inner;
            __builtin_amdgcn_global_load_lds(
                (const __attribute__((address_space(1))) void*)ga,
                (__attribute__((address_space(3))) void*)(As + (w*4+c)*1024), 16, 0, 0);
            __builtin_amdgcn_global_load_lds(
                (const __attribute__((address_space(1))) void*)gb,
                (__attribute__((address_space(3))) void*)(Bs + (w*4+c)*1024), 16, 0, 0);
        }
        __syncthreads();
        #pragma unroll
        for (int kk = 0; kk < 2; ++kk) {
            f16x8 a[4], b[4];
            #pragma unroll
            for (int i = 0; i < 4; ++i) {
                const int rowa = wm + i*16 + fr;
                a[i] = *(const f16x8*)(As + rowa*128 + ((kk*64 + fx) ^ swz));
                const int rowb = wn + i*16 + fr;
                b[i] = *(const f16x8*)(Bs + rowb*128 + ((kk*64 + fx) ^ swz));
            }
            // transposed: mfma(b,a) so lane holds 4 consecutive D cols
            #pragma unroll
            for (int i = 0; i < 4; ++i)
                #pragma unroll
                for (int j = 0; j < 4; ++j)
                    acc[i][j] = __builtin_amdgcn_mfma_f32_16x16x32_f16(b[j], a[i], acc[i][j], 0, 0, 0);
        }
        __syncthreads();
    }

    // ---- epilogue: LDS transpose in 32-row quarters -> contiguous nt stores ----
    float* lbuf = (float*)smem;
    #pragma unroll
    for (int q = 0; q < 4; ++q) {
        if ((w >> 1) == (q >> 1)) {
            const int ib = (q & 1) * 2;
            #pragma unroll
            for (int ii = 0; ii < 2; ++ii) {
                const int rl = ii*16 + fr;
                #pragma unroll
                for (int j = 0; j < 4; ++j) {
                    const int cl = wn + j*16 + g*4;
                    *(f32x4*)(lbuf + rl*LSTRIDE + cl) = acc[ib+ii][j];
                }
            }
        }
        __syncthreads();
        const int qrow0 = (int)bm + q*32;
        const int c4 = (t & 31) * 4;
        #pragma unroll
        for (int p = 0; p < 4; ++p) {
            const int rl = p*8 + (t >> 5);
            const int drow = qrow0 + rl;
            const int dcol = (int)bn + c4;
            f32x4 v = *(const f32x4*)(lbuf + rl*LSTRIDE + c4);
            if (drow < N_G && dcol < N_G)
                __builtin_nontemporal_store(v, (f32x4*)(D + (size_t)drow * N_G + dcol));
        }
        __syncthreads();
    }

    // ---- raster tail: blocks orig<5000 raster gaussians 2*orig, 2*orig+1 ----
    if (orig >= 5000) return;
    #pragma unroll
    for (int g2 = 0; g2 < 2; ++g2) {
        const int n = orig * 2 + g2;
        float al[C_DIM];
        const float4* ap = (const float4*)(alog + n * C_DIM);
        float4 a0 = ap[0], a1 = ap[1];
        al[0]=a0.x; al[1]=a0.y; al[2]=a0.z; al[3]=a0.w;
        al[4]=a1.x; al[5]=a1.y; al[6]=a1.z; al[7]=a1.w;
        float mx = al[0];
        #pragma unroll
        for (int c = 1; c < C_DIM; ++c) mx = fmaxf(mx, al[c]);
        float s = 0.f;
        #pragma unroll
        for (int c = 0; c < C_DIM; ++c) { al[c] = expf(al[c] - mx); s += al[c]; }
        float inv = 1.f / s;
        float r = 0.f, gg = 0.f, b = 0.f;
        #pragma unroll
        for (int c = 0; c < C_DIM; ++c) {
            float ac = al[c] * inv;
            r  += ac * cmeans[c*3+0];
            gg += ac * cmeans[c*3+1];
            b  += ac * cmeans[c*3+2];
        }
        float px = 0.5f * W_IMG * (xyz[n*2+0] + 1.f);
        float py = 0.5f * H_IMG * (xyz[n*2+1] + 1.f);
        float l0 = chol[n*3+0] + 0.5f;
        float l1 = chol[n*3+1];
        float l2 = chol[n*3+2] + 0.5f;
        float c00 = l0*l0, c01 = l0*l1, c11 = l1*l1 + l2*l2;
        float det = c00*c11 - c01*c01;
        float idet = 1.f / det;
        float q0 = c11*idet, q1 = -c01*idet, q2 = c00*idet;
        float op = opac[n];
        int bx = (int)floorf(px);
        int by = (int)floorf(py);

        #pragma unroll
        for (int i = 0; i < 4; ++i) {
            int pix = t + i * 256;
            int tyi = pix >> 5;
            int txi = pix & 31;
            int xi = bx - 16 + txi;
            int yi = by - 16 + tyi;
            float dx = px - ((float)xi + 0.5f);
            float dy = py - ((float)yi + 0.5f);
            float sigma = 0.5f * (q0*dx*dx + q2*dy*dy) + q1*dx*dy;
            float a = fminf(0.999f, op * expf(-sigma));
            bool valid = (sigma >= 0.f) && (a > (1.0f/255.0f)) &&
                         (yi >= 0) && (yi < H_IMG) && (xi >= 0) && (xi < W_IMG);
            if (valid) {
                int idx = yi * W_IMG + xi;
                atomicAdd(img + idx,            a * r);
                atomicAdd(img + HW_IMG + idx,   a * gg);
                atomicAdd(img + 2*HW_IMG + idx, a * b);
            }
        }
    }
}

extern "C" void kernel_launch(void* const* d_in, const int* in_sizes, int n_in,
                              void* d_out, int out_size, void* d_ws, size_t ws_size,
                              hipStream_t stream) {
    const float* alog   = (const float*)d_in[0];
    const float* wproj  = (const float*)d_in[1];
    const float* psi    = (const float*)d_in[2];
    const float* xyz    = (const float*)d_in[3];
    const float* chol   = (const float*)d_in[4];
    const float* opac   = (const float*)d_in[5];
    const float* cmeans = (const float*)d_in[6];
    const float* cbases = (const float*)d_in[7];

    float* out  = (float*)d_out;
    float* img  = out;                                    // [3,512,512]
    float* dmat = out + IMG_SIZE;                         // [N,N]
    float* det  = out + IMG_SIZE + (size_t)N_G * N_G;     // [N,2]

    u16*   Up     = (u16*)d_ws;                           // [NPAD,128]
    u16*   Pp     = Up + (size_t)NPAD * KP;               // [NPAD,128]

    prep_zero<<<848, 256, 0, stream>>>(
        alog, wproj, psi, cbases, Up, Pp, det, img);

    gemm_raster<<<NGEMM, 256, 0, stream>>>(
        Up, Pp, alog, xyz, chol, opac, cmeans, dmat, img);
}